// Round 14
// baseline (1614.041 us; speedup 1.0000x reference)
//
#include <hip/hip_runtime.h>
#include <hip/hip_bf16.h>
#include <math.h>

#define NB 4
#define CE 384
#define NH 12
#define DH 32
#define NPTS 9
#define NLAYERS 2
#define KFG 20
#define KBG 50
#define NITER 10
#define HDIM 64
#define WDIM 64
#define NPIX 4096
#define NCHUNK 32
#define NROW (NPIX + KFG + KBG)
#define TWO_PI 6.283185307179586f

#define AS1 __attribute__((address_space(1)))
#define AS3 __attribute__((address_space(3)))

typedef __attribute__((ext_vector_type(8))) short short8;
typedef __attribute__((ext_vector_type(4))) float float4v;

static __device__ __forceinline__ unsigned short f2bf(float f) {
  __hip_bfloat16 h = __float2bfloat16(f);
  return *reinterpret_cast<unsigned short*>(&h);
}
static __device__ __forceinline__ float bf2f(unsigned short u) {
  unsigned x = ((unsigned)u) << 16;
  return __uint_as_float(x);
}

__device__ __forceinline__ float4 sample4(const float* __restrict__ vb, int xi, int yi, int c) {
  bool valid = (xi >= 0) & (xi < WDIM) & (yi >= 0) & (yi < HDIM);
  int xc = min(max(xi, 0), WDIM - 1), yc = min(max(yi, 0), HDIM - 1);
  float4 g = *(const float4*)(vb + (long)(yc * WDIM + xc) * CE + c);
  if (!valid) { g.x = 0.f; g.y = 0.f; g.z = 0.f; g.w = 0.f; }
  return g;
}

// ---------------- masks ----------------
__global__ void k_masks(const float* __restrict__ pm, const float* __restrict__ sm,
                        float* padf, float* objf, float* notp, float* wfg, float* wbg) {
  int i = blockIdx.x * 256 + threadIdx.x;
  if (i >= NB * NPIX) return;
  float p  = (pm[i] == 255.0f) ? 1.f : 0.f;
  float o  = (sm[i] == 1.0f) ? 1.f : 0.f;
  float np_ = 1.f - p;
  padf[i] = p; objf[i] = o; notp[i] = np_;
  wfg[i] = o * np_;
  wbg[i] = (1.f - o) * np_;
}

// ---------------- LDS-tiled transpose s_x [B,C,N] -> X [B,N,C] ----------------
__global__ __launch_bounds__(256) void k_transpose(const float* __restrict__ sx,
                                                   float* __restrict__ X) {
  __shared__ float tile[64][65];
  int nb = blockIdx.x * 64, cb = blockIdx.y * 64, b = blockIdx.z;
  int t = threadIdx.x;
  for (int idx = t; idx < 64 * 64; idx += 256) {
    int cc = idx >> 6, nn = idx & 63;
    tile[cc][nn] = sx[((long)b * CE + cb + cc) * NPIX + nb + nn];
  }
  __syncthreads();
  for (int idx = t; idx < 64 * 64; idx += 256) {
    int nn = idx >> 6, cc = idx & 63;
    X[((long)b * NPIX + nb + nn) * CE + cb + cc] = tile[cc][nn];
  }
}

// ---------------- xsq (fp64) ----------------
__global__ void k_xsq(const float* __restrict__ X, double* __restrict__ xsq) {
  int row = blockIdx.x; int t = threadIdx.x;
  const float* xr = X + (long)row * CE;
  double s = 0.0;
  for (int i = t; i < CE; i += 64) { double v = (double)xr[i]; s += v * v; }
  #pragma unroll
  for (int o = 32; o > 0; o >>= 1) s += __shfl_down(s, o, 64);
  if (t == 0) xsq[row] = s;
}

// ---------------- pos cumsums + invdt table (LDS-staged; scans bit-identical) ----------------
// grid NB, block 128. Stage padf[b] (16 KB) into LDS coalesced; t<64 column scan, t>=64 row scan.
__global__ __launch_bounds__(128) void k_cums(const float* __restrict__ padf,
                                              float* __restrict__ yvf,
                                              float* __restrict__ xvf,
                                              float* __restrict__ invdt) {
  __shared__ float pad_s[NPIX];
  int b = blockIdx.x; int t = threadIdx.x;
  for (int i = t; i < NPIX; i += 128) pad_s[i] = padf[b * NPIX + i];
  if (b == 0) {
    for (int c = t; c < CE; c += 128) {
      int tt = (c < 192) ? c : c - 192;
      invdt[c] = 1.0f / powf(10000.0f, (float)(2 * (tt / 2)) / 192.0f);
    }
  }
  __syncthreads();
  if (t < 64) {
    int w = t;
    float cum[64]; float tot = 0.f;
    for (int h = 0; h < 64; ++h) {
      float nm = 1.f - pad_s[h * WDIM + w];
      tot += nm; cum[h] = tot;
    }
    float sc = 1.f / (tot + 1e-6f);
    for (int h = 0; h < 64; ++h) yvf[b * NPIX + h * WDIM + w] = cum[h] * sc * TWO_PI;
  } else {
    int h = t - 64;
    float cum[64]; float tot = 0.f;
    for (int w = 0; w < 64; ++w) {
      float nm = 1.f - pad_s[h * WDIM + w];
      tot += nm; cum[w] = tot;
    }
    float sc = 1.f / (tot + 1e-6f);
    for (int w = 0; w < 64; ++w) xvf[b * NPIX + h * WDIM + w] = cum[w] * sc * TWO_PI;
  }
}

// ---------------- kmeans init ----------------
__global__ void k_kinit(const float* __restrict__ X, const float* __restrict__ wts,
                        double* __restrict__ cen, int K) {
  int b = blockIdx.x;
  __shared__ int idx[KBG];
  if (threadIdx.x == 0) {
    int cnt = 0;
    for (int n = 0; n < NPIX && cnt < K; ++n) if (wts[b * NPIX + n] > 0.f) idx[cnt++] = n;
    for (int n = 0; n < NPIX && cnt < K; ++n) if (!(wts[b * NPIX + n] > 0.f)) idx[cnt++] = n;
  }
  __syncthreads();
  for (int i = threadIdx.x; i < K * CE; i += blockDim.x) {
    int k = i / CE, c = i % CE;
    cen[((long)b * K + k) * CE + c] = (double)X[((long)b * NPIX + idx[k]) * CE + c];
  }
}

// ---------------- kmeans distances: 10-center LDS tiles, 1 px/thread, double2 reads --------
// grid (BN/128 = 128, 7), block 128 — 896 blocks of 2 waves = balanced ~7 waves/CU.
// [History: 256thr/1px/10c @448 blocks = 50.5 µs (R13, unbalanced 2-vs-1 blocks/CU);
//  128thr/2px = 68 µs (R11); 5-center split = 107 µs (R12). This config keeps R13's
//  per-thread work with even residency.]
__global__ __launch_bounds__(128) void k_dots(
    const float* __restrict__ X, const double* __restrict__ xsq,
    const double* __restrict__ cenF, const double* __restrict__ cenB,
    double* __restrict__ DF, double* __restrict__ DB, double* __restrict__ denZero) {
  __shared__ double ct[10][CE];
  __shared__ double csq_s[10];
  int z = blockIdx.y;
  int isBg = (z >= 2) ? 1 : 0;
  int k0 = isBg ? (z - 2) * 10 : z * 10;
  int t = threadIdx.x;
  int n = blockIdx.x * 128 + t;
  int b = blockIdx.x >> 5;                 // NPIX/128 = 32 blocks per batch
  if (blockIdx.x == 0 && z == 0) {
    for (int i = t; i < NB * (KFG + KBG); i += 128) denZero[i] = 0.0;
  }
  const double* cb = (isBg ? cenB + (long)b * KBG * CE
                           : cenF + (long)b * KFG * CE) + (long)k0 * CE;
  for (int i = t; i < 10 * CE; i += 128) ct[i / CE][i % CE] = cb[i];
  __syncthreads();
  if (t < 64) {
    for (int kk = 0; kk < 10; ++kk) {
      double s = 0.0;
      for (int c = t; c < CE; c += 64) { double v = ct[kk][c]; s += v * v; }
      #pragma unroll
      for (int o = 32; o > 0; o >>= 1) s += __shfl_down(s, o, 64);
      if (t == 0) csq_s[kk] = s;
    }
  }
  __syncthreads();
  const float* xr = X + (long)n * CE;
  double acc[10];
  #pragma unroll
  for (int k = 0; k < 10; ++k) acc[k] = 0.0;
  for (int c0 = 0; c0 < CE; c0 += 8) {
    double xd[8];
    float4 u = *(const float4*)(xr + c0);
    float4 v = *(const float4*)(xr + c0 + 4);
    xd[0] = u.x; xd[1] = u.y; xd[2] = u.z; xd[3] = u.w;
    xd[4] = v.x; xd[5] = v.y; xd[6] = v.z; xd[7] = v.w;
    #pragma unroll
    for (int k = 0; k < 10; ++k) {
      #pragma unroll
      for (int j = 0; j < 8; j += 2) {
        double2 cv = *(const double2*)(&ct[k][c0 + j]);   // 16B LDS broadcast
        acc[k] += xd[j] * cv.x;
        acc[k] += xd[j + 1] * cv.y;
      }
    }
  }
  double q = xsq[n];
  double* Drow = (isBg ? DB + (long)n * KBG : DF + (long)n * KFG) + k0;
  #pragma unroll
  for (int k = 0; k < 10; ++k) Drow[k] = q - 2.0 * acc[k] + csq_s[k];
}

// ---------------- fused argmin + hist + chunk reduce ----------------
template <int K>
static __device__ __forceinline__ void armred_impl(
    const float* __restrict__ X, const double* __restrict__ D,
    const float* __restrict__ w, double* __restrict__ den,
    double* __restrict__ pout, int b, double* part, int* sa, int* hist) {
  int chunk = blockIdx.x;
  int c0 = blockIdx.y * 128;
  int n0 = chunk * 128;
  int t = threadIdx.x;
  long g = (long)b * NPIX + n0 + t;
  const double* Drow = D + g * K;
  double best = 1.0e300; int bi = 0;
  for (int k = 0; k < K; ++k) {
    double d = Drow[k];
    if (d < best) { best = d; bi = k; }
  }
  int a = (w[g] > 0.f) ? bi : -1;
  sa[t] = a;
  for (int k = 0; k < K; ++k) part[k * 128 + t] = 0.0;
  __syncthreads();
  if (blockIdx.y == 0) {
    if (t < K) hist[t] = 0;
    __syncthreads();
    if (a >= 0) atomicAdd(&hist[a], 1);
    __syncthreads();
    if (t < K && hist[t] > 0) atomicAdd(&den[b * K + t], (double)hist[t]);
  }
  for (int i = 0; i < 128; ++i) {
    int ai = sa[i];
    if (ai >= 0) {
      float x = X[((long)b * NPIX + n0 + i) * CE + c0 + t];
      part[ai * 128 + t] += (double)x;
    }
  }
  __syncthreads();
  for (int k = 0; k < K; ++k)
    pout[(((long)chunk * NB + b) * K + k) * CE + c0 + t] = part[k * 128 + t];
}

__global__ __launch_bounds__(128) void k_armred(
    const float* __restrict__ X, const double* __restrict__ DF, const double* __restrict__ DB,
    const float* __restrict__ wfg, const float* __restrict__ wbg,
    double* __restrict__ denF, double* __restrict__ denB,
    double* __restrict__ PF, double* __restrict__ PB) {
  __shared__ double part[KBG * 128];
  __shared__ int sa[128];
  __shared__ int hist[KBG];
  int z = blockIdx.z;
  if (z < NB) armred_impl<KFG>(X, DF, wfg, denF, PF, z, part, sa, hist);
  else        armred_impl<KBG>(X, DB, wbg, denB, PB, z - NB, part, sa, hist);
}

// ---------------- kmeans reduce stage 2 + center update ----------------
__global__ void k_reduce2f(
    const double* __restrict__ PF, const double* __restrict__ denF,
    const double* __restrict__ srcF, double* __restrict__ dstF, int naF,
    const double* __restrict__ PB, const double* __restrict__ denB,
    const double* __restrict__ srcB, double* __restrict__ dstB, int naB) {
  int i = blockIdx.x * 256 + threadIdx.x;
  const double* P; const double* den; const double* src; double* dst; int K; int idx;
  if (i < naF) { P = PF; den = denF; src = srcF; dst = dstF; K = KFG; idx = i; }
  else if (i - naF < naB) { P = PB; den = denB; src = srcB; dst = dstB; K = KBG; idx = i - naF; }
  else return;
  long stride = (long)NB * K * CE;
  double s = 0.0;
  for (int ch = 0; ch < NCHUNK; ++ch) s += P[(long)ch * stride + idx];
  double d = den[idx / CE];
  dst[idx] = (d > 0.0) ? s / fmax(d, 1e-6) : src[idx];
}

// ---------------- fused pos + bf16 staging ----------------
__global__ void k_cvtQV(const float* __restrict__ X,
                        const float* __restrict__ yvf, const float* __restrict__ xvf,
                        const float* __restrict__ invdt, const float* __restrict__ notp,
                        float* __restrict__ POS,
                        unsigned short* __restrict__ QB, unsigned short* __restrict__ VBin) {
  long i = (long)blockIdx.x * 256 + threadIdx.x;
  if (i >= (long)NB * NPIX * CE) return;
  int c = (int)(i % CE);
  long row = i / CE;
  float p = (c < 192) ? yvf[row] : xvf[row];
  float v = p * invdt[c];
  int tt = (c < 192) ? c : c - 192;
  float r = (tt & 1) ? cosf(v) : sinf(v);
  POS[i] = r;
  float x = X[i];
  QB[i] = f2bf(x + r);
  VBin[i] = f2bf(x * notp[row]);
}

// ---------------- fused per-layer weight convert/transpose + concat bias ----------------
__global__ void k_cvtW_all(
    const float* __restrict__ Wv_l, const float* __restrict__ Woff_l,
    const float* __restrict__ Wa_l, const float* __restrict__ Wout_l,
    const float* __restrict__ Wf1_l, const float* __restrict__ Wf2_l,
    const float* __restrict__ boff_l, const float* __restrict__ ba_l,
    unsigned short* __restrict__ W0, unsigned short* __restrict__ W1,
    unsigned short* __restrict__ W3, unsigned short* __restrict__ W4,
    unsigned short* __restrict__ W5, float* __restrict__ biasCat) {
  int i = blockIdx.x * 256 + threadIdx.x;
  const int S = 147456, SF = 442368;
  if (i < S) {
    int n = i / 384, k = i % 384;
    W0[i] = f2bf(Wv_l[(long)k * 384 + n]);
  } else if (i < 2 * S) {
    int j = i - S; int n = j / 384, k = j % 384;
    float v = 0.f;
    if (n < 216) v = Woff_l[(long)k * 216 + n];
    else if (n < 324) v = Wa_l[(long)k * 108 + (n - 216)];
    W1[j] = f2bf(v);
  } else if (i < 3 * S) {
    int j = i - 2 * S; int n = j / 384, k = j % 384;
    W3[j] = f2bf(Wout_l[(long)k * 384 + n]);
  } else if (i < 3 * S + SF) {
    int j = i - 3 * S; int n = j / 384, k = j % 384;
    W4[j] = f2bf(Wf1_l[(long)k * 1152 + n]);
  } else if (i < 3 * S + 2 * SF) {
    int j = i - 3 * S - SF; int n = j / 1152, k = j % 1152;
    W5[j] = f2bf(Wf2_l[(long)k * 384 + n]);
  } else if (i < 3 * S + 2 * SF + 324) {
    int j = i - 3 * S - 2 * SF;
    biasCat[j] = (j < 216) ? boff_l[j] : ba_l[j - 216];
  }
}

// ---------------- bf16 MFMA GEMM: C = A @ Bt^T (+bias)(+relu) ----------------
// Staging via global_load_lds width=16 (DMA direct to LDS, contiguous 64B rows).
__global__ __launch_bounds__(256) void k_gemm_bf(
    const unsigned short* __restrict__ A, const unsigned short* __restrict__ Bt,
    const float* __restrict__ bias, float* __restrict__ Cf, unsigned short* __restrict__ Cb,
    int M, int K, int N, int relu) {
  __shared__ unsigned short As[128 * 32];
  __shared__ unsigned short Bs[128 * 32];
  int m0 = blockIdx.y * 128, n0 = blockIdx.x * 128;
  int t = threadIdx.x;
  int w = t >> 6, l = t & 63;
  int wm = w >> 1, wn = w & 1;
  int half = l >> 4, lr = l & 15;
  float4v acc[4][4] = {};
  for (int k0 = 0; k0 < K; k0 += 32) {
    #pragma unroll
    for (int i = 0; i < 2; ++i) {
      int c = w * 64 + i * 256 + l;           // 0..511
      int r = c >> 2, part = c & 3;
      int ldsOff = (w * 64 + i * 256) * 8;    // shorts; lane adds l*16 bytes
      __builtin_amdgcn_global_load_lds(
          (const AS1 unsigned int*)(A + (size_t)(m0 + r) * K + k0 + part * 8),
          (AS3 unsigned int*)(As + ldsOff), 16, 0, 0);
      __builtin_amdgcn_global_load_lds(
          (const AS1 unsigned int*)(Bt + (size_t)(n0 + r) * K + k0 + part * 8),
          (AS3 unsigned int*)(Bs + ldsOff), 16, 0, 0);
    }
    __syncthreads();
    short8 af[4], bfr[4];
    #pragma unroll
    for (int am = 0; am < 4; ++am)
      af[am] = *(const short8*)(&As[(wm * 64 + am * 16 + lr) * 32 + half * 8]);
    #pragma unroll
    for (int bn = 0; bn < 4; ++bn)
      bfr[bn] = *(const short8*)(&Bs[(wn * 64 + bn * 16 + lr) * 32 + half * 8]);
    #pragma unroll
    for (int am = 0; am < 4; ++am)
      #pragma unroll
      for (int bn = 0; bn < 4; ++bn)
        acc[am][bn] = __builtin_amdgcn_mfma_f32_16x16x32_bf16(af[am], bfr[bn], acc[am][bn], 0, 0, 0);
    __syncthreads();
  }
  #pragma unroll
  for (int am = 0; am < 4; ++am) {
    #pragma unroll
    for (int bn = 0; bn < 4; ++bn) {
      int gc = n0 + wn * 64 + bn * 16 + lr;
      if (gc < N) {
        float bv = bias ? bias[gc] : 0.f;
        int gr0 = m0 + wm * 64 + am * 16 + half * 4;
        #pragma unroll
        for (int r = 0; r < 4; ++r) {
          float v = acc[am][bn][r] + bv;
          if (relu) v = fmaxf(v, 0.f);
          size_t oi = (size_t)(gr0 + r) * N + gc;
          if (Cf) Cf[oi] = v;
          else Cb[oi] = f2bf(v);
        }
      }
    }
  }
}

// ---------------- coords+softmax: one thread per (row, head) ----------------
__global__ void k_coords(const unsigned short* __restrict__ OAB, float4* __restrict__ CRD) {
  int idx = blockIdx.x * 256 + threadIdx.x;
  if (idx >= NB * NPIX * NH) return;
  int row = idx / NH, h = idx % NH;
  int n = row & (NPIX - 1);
  int hh = n >> 6, ww = n & 63;
  float refx = ((float)ww + 0.5f) / (float)WDIM;
  float refy = ((float)hh + 0.5f) / (float)HDIM;
  const unsigned short* oab = OAB + (size_t)row * 324;
  float f[NPTS];
  #pragma unroll
  for (int j = 0; j < NPTS; ++j) f[j] = bf2f(oab[216 + h * 9 + j]);
  float m = f[0];
  #pragma unroll
  for (int j = 1; j < NPTS; ++j) m = fmaxf(m, f[j]);
  float s = 0.f;
  #pragma unroll
  for (int j = 0; j < NPTS; ++j) { f[j] = expf(f[j] - m); s += f[j]; }
  float inv = 1.f / s;
  float4* crd = CRD + (size_t)row * 108 + h * 9;
  #pragma unroll
  for (int p = 0; p < NPTS; ++p) {
    float ox = bf2f(oab[h * 18 + p * 2 + 0]);
    float oy = bf2f(oab[h * 18 + p * 2 + 1]);
    float lx = refx + ox / (float)WDIM;
    float ly = refy + oy / (float)HDIM;
    float xs = lx * (float)WDIM - 0.5f;
    float ys = ly * (float)HDIM - 0.5f;
    float x0f = floorf(xs), y0f = floorf(ys);
    int x0 = (int)x0f, y0 = (int)y0f;
    float4 o;
    o.x = xs - x0f;
    o.y = ys - y0f;
    o.z = f[p] * inv;
    o.w = __int_as_float((y0 << 16) | (x0 & 0xFFFF));
    crd[p] = o;
  }
}

// ---------------- gather: 4 channels per thread, float4 gathers ----------------
__global__ __launch_bounds__(256) void k_gather(
    const float* __restrict__ V, const float4* __restrict__ CRD,
    uint2* __restrict__ ATTu) {
  int idx = blockIdx.x * 256 + threadIdx.x;
  if (idx >= NB * NPIX * (CE / 4)) return;
  int row = idx / (CE / 4), cq = idx % (CE / 4);
  int c = cq * 4;
  int h = c >> 5;
  int b = row >> 12;
  const float* vb = V + (size_t)b * NPIX * CE;
  const float4* crd = CRD + (size_t)row * 108 + h * 9;
  float a0 = 0.f, a1 = 0.f, a2 = 0.f, a3 = 0.f;
  #pragma unroll
  for (int p = 0; p < NPTS; ++p) {
    float4 o = crd[p];
    int pk = __float_as_int(o.w);
    int x0 = (int)(short)(pk & 0xFFFF);
    int y0 = pk >> 16;
    float wx = o.x, wy = o.y, aw = o.z;
    float4 g00 = sample4(vb, x0,     y0,     c);
    float4 g01 = sample4(vb, x0 + 1, y0,     c);
    float4 g10 = sample4(vb, x0,     y0 + 1, c);
    float4 g11 = sample4(vb, x0 + 1, y0 + 1, c);
    float w00 = (1.f - wx) * (1.f - wy), w01 = wx * (1.f - wy);
    float w10 = (1.f - wx) * wy,         w11 = wx * wy;
    a0 += aw * (g00.x * w00 + g01.x * w01 + g10.x * w10 + g11.x * w11);
    a1 += aw * (g00.y * w00 + g01.y * w01 + g10.y * w10 + g11.y * w11);
    a2 += aw * (g00.z * w00 + g01.z * w01 + g10.z * w10 + g11.z * w11);
    a3 += aw * (g00.w * w00 + g01.w * w01 + g10.w * w10 + g11.w * w11);
  }
  uint2 pk2;
  pk2.x = (unsigned)f2bf(a0) | ((unsigned)f2bf(a1) << 16);
  pk2.y = (unsigned)f2bf(a2) | ((unsigned)f2bf(a3) << 16);
  ATTu[(size_t)row * (CE / 4) + cq] = pk2;
}

// ---------------- LayerNorm(X + T), 4 rows/block, fused epilogues ----------------
__global__ __launch_bounds__(256) void k_ln(
    float* __restrict__ X, const float* __restrict__ T,
    const float* __restrict__ g, const float* __restrict__ bb,
    unsigned short* __restrict__ xbOut,
    const float* __restrict__ posp, const float* __restrict__ notp,
    unsigned short* __restrict__ qb, unsigned short* __restrict__ vbin,
    float* __restrict__ outp) {
  int t = threadIdx.x;
  int row = blockIdx.x * 4 + (t >> 6);
  int lane = t & 63;
  float* xr = X + (long)row * CE;
  const float* tr = T + (long)row * CE;
  float v[6]; float s = 0.f;
  #pragma unroll
  for (int i = 0; i < 6; ++i) { v[i] = xr[lane + 64 * i] + tr[lane + 64 * i]; s += v[i]; }
  #pragma unroll
  for (int o = 32; o > 0; o >>= 1) s += __shfl_down(s, o, 64);
  s = __shfl(s, 0, 64);
  float m = s / (float)CE;
  float var = 0.f;
  #pragma unroll
  for (int i = 0; i < 6; ++i) { float d = v[i] - m; var += d * d; }
  #pragma unroll
  for (int o = 32; o > 0; o >>= 1) var += __shfl_down(var, o, 64);
  var = __shfl(var, 0, 64);
  float rst = rsqrtf(var / (float)CE + 1e-5f);
  float nprow = notp ? notp[row] : 0.f;
  int b = row >> 12, n = row & (NPIX - 1);
  #pragma unroll
  for (int i = 0; i < 6; ++i) {
    int c = lane + 64 * i;
    float xn = (v[i] - m) * rst * g[c] + bb[c];
    if (outp) outp[((long)b * NROW + n) * CE + c] = xn;
    else xr[c] = xn;
    if (xbOut) xbOut[(long)row * CE + c] = f2bf(xn);
    if (qb) {
      qb[(long)row * CE + c] = f2bf(xn + posp[(long)row * CE + c]);
      vbin[(long)row * CE + c] = f2bf(xn * nprow);
    }
  }
}

// ---------------- centers -> output ----------------
__global__ void k_out_cen(const double* __restrict__ fg, const double* __restrict__ bg,
                          float* __restrict__ out) {
  int i = blockIdx.x * 256 + threadIdx.x;
  const int tot = NB * (KFG + KBG) * CE;
  if (i >= tot) return;
  int c = i % CE;
  int r = i / CE;
  int rr = r % (KFG + KBG);
  int b = r / (KFG + KBG);
  float v;
  if (rr < KFG) v = (float)fg[((long)b * KFG + rr) * CE + c];
  else v = (float)bg[((long)b * KBG + (rr - KFG)) * CE + c];
  out[((long)b * NROW + NPIX + rr) * CE + c] = v;
}

extern "C" void kernel_launch(void* const* d_in, const int* in_sizes, int n_in,
                              void* d_out, int out_size, void* d_ws, size_t ws_size,
                              hipStream_t stream) {
  (void)in_sizes; (void)n_in; (void)out_size; (void)ws_size;
  const float* s_x  = (const float*)d_in[0];
  const float* s_pm = (const float*)d_in[1];
  const float* s_sm = (const float*)d_in[2];
  const float* Wv   = (const float*)d_in[3];
  const float* bv   = (const float*)d_in[4];
  const float* Woff = (const float*)d_in[5];
  const float* boff = (const float*)d_in[6];
  const float* Wa   = (const float*)d_in[7];
  const float* ba   = (const float*)d_in[8];
  const float* Wout = (const float*)d_in[9];
  const float* bout = (const float*)d_in[10];
  const float* ln1g = (const float*)d_in[11];
  const float* ln1b = (const float*)d_in[12];
  const float* Wf1  = (const float*)d_in[13];
  const float* Wf2  = (const float*)d_in[14];
  const float* ln2g = (const float*)d_in[15];
  const float* ln2b = (const float*)d_in[16];
  float* out = (float*)d_out;
  char* pb = (char*)d_ws;

  const long BN  = (long)NB * NPIX;      // 16384
  const long BNC = BN * CE;              // 6291456

  float* X    = (float*)pb; pb += BNC * 4;
  float* POS  = (float*)pb; pb += BNC * 4;
  float* V    = (float*)pb; pb += BNC * 4;
  float* T2   = (float*)pb; pb += BNC * 4;
  double* PF  = (double*)V;    // NCHUNK*NB*KFG*CE*8 = 7.9 MB  (< 24 MB)
  double* PB  = (double*)T2;   // NCHUNK*NB*KBG*CE*8 = 19.7 MB (< 24 MB)
  unsigned short* QB   = (unsigned short*)pb; pb += BNC * 2;
  unsigned short* VBin = (unsigned short*)pb; pb += BNC * 2;
  unsigned short* T1b  = (unsigned short*)pb; pb += BNC * 2;
  unsigned short* Zbf  = QB;   // FFN hidden aliases QB+VBin+T1b
  unsigned short* XB   = (unsigned short*)pb; pb += BNC * 2;
  unsigned short* OAB  = (unsigned short*)pb; pb += BN * 324 * 2;
  float4* CRD = (float4*)pb; pb += BN * 108 * 16;
  const int S_W = 147456, S_F = 442368;
  unsigned short* WT[NLAYERS][5];
  float* biasCat[NLAYERS];
  for (int l = 0; l < NLAYERS; ++l) {
    WT[l][0] = (unsigned short*)pb; pb += S_W * 2;
    WT[l][1] = (unsigned short*)pb; pb += S_W * 2;
    WT[l][2] = (unsigned short*)pb; pb += S_W * 2;
    WT[l][3] = (unsigned short*)pb; pb += S_F * 2;
    WT[l][4] = (unsigned short*)pb; pb += S_F * 2;
    biasCat[l] = (float*)pb; pb += 324 * 4;
  }
  float* padf = (float*)pb; pb += BN * 4;
  float* objf = (float*)pb; pb += BN * 4;
  float* notp = (float*)pb; pb += BN * 4;
  float* wfg  = (float*)pb; pb += BN * 4;
  float* wbg  = (float*)pb; pb += BN * 4;
  float* yvf  = (float*)pb; pb += BN * 4;
  float* xvf  = (float*)pb; pb += BN * 4;
  float* invdt = (float*)pb; pb += CE * 4;
  pb = (char*)(((size_t)pb + 7) & ~(size_t)7);
  double* xsq  = (double*)pb; pb += BN * 8;
  double* DF   = (double*)pb; pb += BN * KFG * 8;
  double* DB   = (double*)pb; pb += BN * KBG * 8;
  double* cFgA = (double*)pb; pb += (long)NB * KFG * CE * 8;
  double* cFgB = (double*)pb; pb += (long)NB * KFG * CE * 8;
  double* cBgA = (double*)pb; pb += (long)NB * KBG * CE * 8;
  double* cBgB = (double*)pb; pb += (long)NB * KBG * CE * 8;
  double* denF = (double*)pb; pb += NB * KFG * 8;
  double* denB = (double*)pb; pb += NB * KBG * 8;   // contiguous after denF

  int bn = (int)BN;
  int cvtBlocks = (int)((BNC + 255) / 256);

  k_masks<<<(bn + 255) / 256, 256, 0, stream>>>(s_pm, s_sm, padf, objf, notp, wfg, wbg);
  k_transpose<<<dim3(NPIX / 64, CE / 64, NB), 256, 0, stream>>>(s_x, X);
  k_xsq<<<bn, 64, 0, stream>>>(X, xsq);
  k_cums<<<NB, 128, 0, stream>>>(padf, yvf, xvf, invdt);
  k_cvtQV<<<cvtBlocks, 256, 0, stream>>>(X, yvf, xvf, invdt, notp, POS, QB, VBin);

  const int CVTW_TOT = 3 * S_W + 2 * S_F + 324;
  for (int l = 0; l < NLAYERS; ++l) {
    k_cvtW_all<<<(CVTW_TOT + 255) / 256, 256, 0, stream>>>(
        Wv + (long)l * CE * CE, Woff + (long)l * CE * 216, Wa + (long)l * CE * 108,
        Wout + (long)l * CE * CE, Wf1 + (long)l * CE * 1152, Wf2 + (long)l * 1152 * CE,
        boff + l * 216, ba + l * 108,
        WT[l][0], WT[l][1], WT[l][2], WT[l][3], WT[l][4], biasCat[l]);
  }

  // ---- kmeans: dots -> (argmin+hist+reduce1) -> reduce2+final ----
  double *srcF = cFgA, *dstF = cFgB, *srcB = cBgA, *dstB = cBgB;
  k_kinit<<<NB, 256, 0, stream>>>(X, wfg, srcF, KFG);
  k_kinit<<<NB, 256, 0, stream>>>(X, wbg, srcB, KBG);
  int naF = NB * KFG * CE, naB = NB * KBG * CE;
  for (int it = 0; it < NITER; ++it) {
    k_dots<<<dim3(bn / 128, 7), 128, 0, stream>>>(X, xsq, srcF, srcB, DF, DB, denF);
    k_armred<<<dim3(NCHUNK, CE / 128, NB * 2), 128, 0, stream>>>(
        X, DF, DB, wfg, wbg, denF, denB, PF, PB);
    k_reduce2f<<<(naF + naB + 255) / 256, 256, 0, stream>>>(
        PF, denF, srcF, dstF, naF, PB, denB, srcB, dstB, naB);
    double* tmp;
    tmp = srcF; srcF = dstF; dstF = tmp;
    tmp = srcB; srcB = dstB; dstB = tmp;
  }
  double* fgC = srcF; double* bgC = srcB;

  // ---- layers ----
  for (int l = 0; l < NLAYERS; ++l) {
    const float* bv_l   = bv   + l * CE;
    const float* bout_l = bout + l * CE;
    int last = (l == NLAYERS - 1);

    k_gemm_bf<<<dim3(3, 128), 256, 0, stream>>>(VBin, WT[l][0], bv_l, V, (unsigned short*)nullptr,
                                                bn, CE, 384, 0);
    k_gemm_bf<<<dim3(3, 128), 256, 0, stream>>>(QB, WT[l][1], biasCat[l], (float*)nullptr, OAB,
                                                bn, CE, 324, 0);
    k_coords<<<(bn * NH + 255) / 256, 256, 0, stream>>>(OAB, CRD);
    k_gather<<<(bn * (CE / 4) + 255) / 256, 256, 0, stream>>>(V, CRD, (uint2*)T1b);
    k_gemm_bf<<<dim3(3, 128), 256, 0, stream>>>(T1b, WT[l][2], bout_l, T2, (unsigned short*)nullptr,
                                                bn, CE, 384, 0);
    k_ln<<<bn / 4, 256, 0, stream>>>(X, T2, ln1g + l * CE, ln1b + l * CE,
                                     XB, (const float*)nullptr, (const float*)nullptr,
                                     (unsigned short*)nullptr, (unsigned short*)nullptr,
                                     (float*)nullptr);
    k_gemm_bf<<<dim3(9, 128), 256, 0, stream>>>(XB, WT[l][3], (const float*)nullptr,
                                                (float*)nullptr, Zbf, bn, CE, 1152, 1);
    k_gemm_bf<<<dim3(3, 128), 256, 0, stream>>>(Zbf, WT[l][4], (const float*)nullptr,
                                                T2, (unsigned short*)nullptr, bn, 1152, 384, 0);
    if (!last) {
      k_ln<<<bn / 4, 256, 0, stream>>>(X, T2, ln2g + l * CE, ln2b + l * CE,
                                       (unsigned short*)nullptr, POS, notp, QB, VBin,
                                       (float*)nullptr);
    } else {
      k_ln<<<bn / 4, 256, 0, stream>>>(X, T2, ln2g + l * CE, ln2b + l * CE,
                                       (unsigned short*)nullptr, (const float*)nullptr,
                                       (const float*)nullptr, (unsigned short*)nullptr,
                                       (unsigned short*)nullptr, out);
    }
  }

  k_out_cen<<<(NB * (KFG + KBG) * CE + 255) / 256, 256, 0, stream>>>(fgC, bgC, out);
}

// Round 15
// 1577.128 us; speedup vs baseline: 1.0234x; 1.0234x over previous
//
#include <hip/hip_runtime.h>
#include <hip/hip_bf16.h>
#include <math.h>

#define NB 4
#define CE 384
#define NH 12
#define DH 32
#define NPTS 9
#define NLAYERS 2
#define KFG 20
#define KBG 50
#define NITER 10
#define HDIM 64
#define WDIM 64
#define NPIX 4096
#define NCHUNK 32
#define NROW (NPIX + KFG + KBG)
#define TWO_PI 6.283185307179586f

#define AS1 __attribute__((address_space(1)))
#define AS3 __attribute__((address_space(3)))

typedef __attribute__((ext_vector_type(8))) short short8;
typedef __attribute__((ext_vector_type(4))) float float4v;

static __device__ __forceinline__ unsigned short f2bf(float f) {
  __hip_bfloat16 h = __float2bfloat16(f);
  return *reinterpret_cast<unsigned short*>(&h);
}
static __device__ __forceinline__ float bf2f(unsigned short u) {
  unsigned x = ((unsigned)u) << 16;
  return __uint_as_float(x);
}

__device__ __forceinline__ float4 sample4(const float* __restrict__ vb, int xi, int yi, int c) {
  bool valid = (xi >= 0) & (xi < WDIM) & (yi >= 0) & (yi < HDIM);
  int xc = min(max(xi, 0), WDIM - 1), yc = min(max(yi, 0), HDIM - 1);
  float4 g = *(const float4*)(vb + (long)(yc * WDIM + xc) * CE + c);
  if (!valid) { g.x = 0.f; g.y = 0.f; g.z = 0.f; g.w = 0.f; }
  return g;
}

// ---------------- masks ----------------
__global__ void k_masks(const float* __restrict__ pm, const float* __restrict__ sm,
                        float* padf, float* objf, float* notp, float* wfg, float* wbg) {
  int i = blockIdx.x * 256 + threadIdx.x;
  if (i >= NB * NPIX) return;
  float p  = (pm[i] == 255.0f) ? 1.f : 0.f;
  float o  = (sm[i] == 1.0f) ? 1.f : 0.f;
  float np_ = 1.f - p;
  padf[i] = p; objf[i] = o; notp[i] = np_;
  wfg[i] = o * np_;
  wbg[i] = (1.f - o) * np_;
}

// ---------------- LDS-tiled transpose s_x [B,C,N] -> X [B,N,C] ----------------
__global__ __launch_bounds__(256) void k_transpose(const float* __restrict__ sx,
                                                   float* __restrict__ X) {
  __shared__ float tile[64][65];
  int nb = blockIdx.x * 64, cb = blockIdx.y * 64, b = blockIdx.z;
  int t = threadIdx.x;
  for (int idx = t; idx < 64 * 64; idx += 256) {
    int cc = idx >> 6, nn = idx & 63;
    tile[cc][nn] = sx[((long)b * CE + cb + cc) * NPIX + nb + nn];
  }
  __syncthreads();
  for (int idx = t; idx < 64 * 64; idx += 256) {
    int nn = idx >> 6, cc = idx & 63;
    X[((long)b * NPIX + nb + nn) * CE + cb + cc] = tile[cc][nn];
  }
}

// ---------------- xsq (fp64) ----------------
__global__ void k_xsq(const float* __restrict__ X, double* __restrict__ xsq) {
  int row = blockIdx.x; int t = threadIdx.x;
  const float* xr = X + (long)row * CE;
  double s = 0.0;
  for (int i = t; i < CE; i += 64) { double v = (double)xr[i]; s += v * v; }
  #pragma unroll
  for (int o = 32; o > 0; o >>= 1) s += __shfl_down(s, o, 64);
  if (t == 0) xsq[row] = s;
}

// ---------------- pos cumsums + invdt table (LDS-staged; scans bit-identical) ----------------
__global__ __launch_bounds__(128) void k_cums(const float* __restrict__ padf,
                                              float* __restrict__ yvf,
                                              float* __restrict__ xvf,
                                              float* __restrict__ invdt) {
  __shared__ float pad_s[NPIX];
  int b = blockIdx.x; int t = threadIdx.x;
  for (int i = t; i < NPIX; i += 128) pad_s[i] = padf[b * NPIX + i];
  if (b == 0) {
    for (int c = t; c < CE; c += 128) {
      int tt = (c < 192) ? c : c - 192;
      invdt[c] = 1.0f / powf(10000.0f, (float)(2 * (tt / 2)) / 192.0f);
    }
  }
  __syncthreads();
  if (t < 64) {
    int w = t;
    float cum[64]; float tot = 0.f;
    for (int h = 0; h < 64; ++h) {
      float nm = 1.f - pad_s[h * WDIM + w];
      tot += nm; cum[h] = tot;
    }
    float sc = 1.f / (tot + 1e-6f);
    for (int h = 0; h < 64; ++h) yvf[b * NPIX + h * WDIM + w] = cum[h] * sc * TWO_PI;
  } else {
    int h = t - 64;
    float cum[64]; float tot = 0.f;
    for (int w = 0; w < 64; ++w) {
      float nm = 1.f - pad_s[h * WDIM + w];
      tot += nm; cum[w] = tot;
    }
    float sc = 1.f / (tot + 1e-6f);
    for (int w = 0; w < 64; ++w) xvf[b * NPIX + h * WDIM + w] = cum[w] * sc * TWO_PI;
  }
}

// ---------------- kmeans init ----------------
__global__ void k_kinit(const float* __restrict__ X, const float* __restrict__ wts,
                        double* __restrict__ cen, int K) {
  int b = blockIdx.x;
  __shared__ int idx[KBG];
  if (threadIdx.x == 0) {
    int cnt = 0;
    for (int n = 0; n < NPIX && cnt < K; ++n) if (wts[b * NPIX + n] > 0.f) idx[cnt++] = n;
    for (int n = 0; n < NPIX && cnt < K; ++n) if (!(wts[b * NPIX + n] > 0.f)) idx[cnt++] = n;
  }
  __syncthreads();
  for (int i = threadIdx.x; i < K * CE; i += blockDim.x) {
    int k = i / CE, c = i % CE;
    cen[((long)b * K + k) * CE + c] = (double)X[((long)b * NPIX + idx[k]) * CE + c];
  }
}

// ---------------- kmeans distances: 10-center LDS tiles, 1 px/thread, double2 reads --------
// grid (BN/256, 7), block 256. BEST-MEASURED CONFIG — do not change without A/B:
//   256thr/1px/10c @448blk = 50.5 µs (R13)  <  128thr/1px @896blk = 55.5 (R14, 2x center
//   staging traffic)  <  128thr/2px = 68 (R11)  <  5-center split = 107 (R12).
__global__ __launch_bounds__(256) void k_dots(
    const float* __restrict__ X, const double* __restrict__ xsq,
    const double* __restrict__ cenF, const double* __restrict__ cenB,
    double* __restrict__ DF, double* __restrict__ DB, double* __restrict__ denZero) {
  __shared__ double ct[10][CE];
  __shared__ double csq_s[10];
  int z = blockIdx.y;
  int isBg = (z >= 2) ? 1 : 0;
  int k0 = isBg ? (z - 2) * 10 : z * 10;
  int t = threadIdx.x;
  int n = blockIdx.x * 256 + t;
  int b = blockIdx.x >> 4;
  if (blockIdx.x == 0 && z == 0) {
    for (int i = t; i < NB * (KFG + KBG); i += 256) denZero[i] = 0.0;
  }
  const double* cb = (isBg ? cenB + (long)b * KBG * CE
                           : cenF + (long)b * KFG * CE) + (long)k0 * CE;
  for (int i = t; i < 10 * CE; i += 256) ct[i / CE][i % CE] = cb[i];
  __syncthreads();
  if (t < 64) {
    for (int kk = 0; kk < 10; ++kk) {
      double s = 0.0;
      for (int c = t; c < CE; c += 64) { double v = ct[kk][c]; s += v * v; }
      #pragma unroll
      for (int o = 32; o > 0; o >>= 1) s += __shfl_down(s, o, 64);
      if (t == 0) csq_s[kk] = s;
    }
  }
  __syncthreads();
  const float* xr = X + (long)n * CE;
  double acc[10];
  #pragma unroll
  for (int k = 0; k < 10; ++k) acc[k] = 0.0;
  for (int c0 = 0; c0 < CE; c0 += 8) {
    double xd[8];
    float4 u = *(const float4*)(xr + c0);
    float4 v = *(const float4*)(xr + c0 + 4);
    xd[0] = u.x; xd[1] = u.y; xd[2] = u.z; xd[3] = u.w;
    xd[4] = v.x; xd[5] = v.y; xd[6] = v.z; xd[7] = v.w;
    #pragma unroll
    for (int k = 0; k < 10; ++k) {
      #pragma unroll
      for (int j = 0; j < 8; j += 2) {
        double2 cv = *(const double2*)(&ct[k][c0 + j]);   // 16B LDS broadcast
        acc[k] += xd[j] * cv.x;
        acc[k] += xd[j + 1] * cv.y;
      }
    }
  }
  double q = xsq[n];
  double* Drow = (isBg ? DB + (long)n * KBG : DF + (long)n * KFG) + k0;
  #pragma unroll
  for (int k = 0; k < 10; ++k) Drow[k] = q - 2.0 * acc[k] + csq_s[k];
}

// ---------------- fused argmin + hist + chunk reduce ----------------
template <int K>
static __device__ __forceinline__ void armred_impl(
    const float* __restrict__ X, const double* __restrict__ D,
    const float* __restrict__ w, double* __restrict__ den,
    double* __restrict__ pout, int b, double* part, int* sa, int* hist) {
  int chunk = blockIdx.x;
  int c0 = blockIdx.y * 128;
  int n0 = chunk * 128;
  int t = threadIdx.x;
  long g = (long)b * NPIX + n0 + t;
  const double* Drow = D + g * K;
  double best = 1.0e300; int bi = 0;
  for (int k = 0; k < K; ++k) {
    double d = Drow[k];
    if (d < best) { best = d; bi = k; }
  }
  int a = (w[g] > 0.f) ? bi : -1;
  sa[t] = a;
  for (int k = 0; k < K; ++k) part[k * 128 + t] = 0.0;
  __syncthreads();
  if (blockIdx.y == 0) {
    if (t < K) hist[t] = 0;
    __syncthreads();
    if (a >= 0) atomicAdd(&hist[a], 1);
    __syncthreads();
    if (t < K && hist[t] > 0) atomicAdd(&den[b * K + t], (double)hist[t]);
  }
  for (int i = 0; i < 128; ++i) {
    int ai = sa[i];
    if (ai >= 0) {
      float x = X[((long)b * NPIX + n0 + i) * CE + c0 + t];
      part[ai * 128 + t] += (double)x;
    }
  }
  __syncthreads();
  for (int k = 0; k < K; ++k)
    pout[(((long)chunk * NB + b) * K + k) * CE + c0 + t] = part[k * 128 + t];
}

__global__ __launch_bounds__(128) void k_armred(
    const float* __restrict__ X, const double* __restrict__ DF, const double* __restrict__ DB,
    const float* __restrict__ wfg, const float* __restrict__ wbg,
    double* __restrict__ denF, double* __restrict__ denB,
    double* __restrict__ PF, double* __restrict__ PB) {
  __shared__ double part[KBG * 128];
  __shared__ int sa[128];
  __shared__ int hist[KBG];
  int z = blockIdx.z;
  if (z < NB) armred_impl<KFG>(X, DF, wfg, denF, PF, z, part, sa, hist);
  else        armred_impl<KBG>(X, DB, wbg, denB, PB, z - NB, part, sa, hist);
}

// ---------------- kmeans reduce stage 2 + center update ----------------
__global__ void k_reduce2f(
    const double* __restrict__ PF, const double* __restrict__ denF,
    const double* __restrict__ srcF, double* __restrict__ dstF, int naF,
    const double* __restrict__ PB, const double* __restrict__ denB,
    const double* __restrict__ srcB, double* __restrict__ dstB, int naB) {
  int i = blockIdx.x * 256 + threadIdx.x;
  const double* P; const double* den; const double* src; double* dst; int K; int idx;
  if (i < naF) { P = PF; den = denF; src = srcF; dst = dstF; K = KFG; idx = i; }
  else if (i - naF < naB) { P = PB; den = denB; src = srcB; dst = dstB; K = KBG; idx = i - naF; }
  else return;
  long stride = (long)NB * K * CE;
  double s = 0.0;
  for (int ch = 0; ch < NCHUNK; ++ch) s += P[(long)ch * stride + idx];
  double d = den[idx / CE];
  dst[idx] = (d > 0.0) ? s / fmax(d, 1e-6) : src[idx];
}

// ---------------- fused pos + bf16 staging ----------------
__global__ void k_cvtQV(const float* __restrict__ X,
                        const float* __restrict__ yvf, const float* __restrict__ xvf,
                        const float* __restrict__ invdt, const float* __restrict__ notp,
                        float* __restrict__ POS,
                        unsigned short* __restrict__ QB, unsigned short* __restrict__ VBin) {
  long i = (long)blockIdx.x * 256 + threadIdx.x;
  if (i >= (long)NB * NPIX * CE) return;
  int c = (int)(i % CE);
  long row = i / CE;
  float p = (c < 192) ? yvf[row] : xvf[row];
  float v = p * invdt[c];
  int tt = (c < 192) ? c : c - 192;
  float r = (tt & 1) ? cosf(v) : sinf(v);
  POS[i] = r;
  float x = X[i];
  QB[i] = f2bf(x + r);
  VBin[i] = f2bf(x * notp[row]);
}

// ---------------- fused per-layer weight convert/transpose + concat bias ----------------
__global__ void k_cvtW_all(
    const float* __restrict__ Wv_l, const float* __restrict__ Woff_l,
    const float* __restrict__ Wa_l, const float* __restrict__ Wout_l,
    const float* __restrict__ Wf1_l, const float* __restrict__ Wf2_l,
    const float* __restrict__ boff_l, const float* __restrict__ ba_l,
    unsigned short* __restrict__ W0, unsigned short* __restrict__ W1,
    unsigned short* __restrict__ W3, unsigned short* __restrict__ W4,
    unsigned short* __restrict__ W5, float* __restrict__ biasCat) {
  int i = blockIdx.x * 256 + threadIdx.x;
  const int S = 147456, SF = 442368;
  if (i < S) {
    int n = i / 384, k = i % 384;
    W0[i] = f2bf(Wv_l[(long)k * 384 + n]);
  } else if (i < 2 * S) {
    int j = i - S; int n = j / 384, k = j % 384;
    float v = 0.f;
    if (n < 216) v = Woff_l[(long)k * 216 + n];
    else if (n < 324) v = Wa_l[(long)k * 108 + (n - 216)];
    W1[j] = f2bf(v);
  } else if (i < 3 * S) {
    int j = i - 2 * S; int n = j / 384, k = j % 384;
    W3[j] = f2bf(Wout_l[(long)k * 384 + n]);
  } else if (i < 3 * S + SF) {
    int j = i - 3 * S; int n = j / 384, k = j % 384;
    W4[j] = f2bf(Wf1_l[(long)k * 1152 + n]);
  } else if (i < 3 * S + 2 * SF) {
    int j = i - 3 * S - SF; int n = j / 1152, k = j % 1152;
    W5[j] = f2bf(Wf2_l[(long)k * 384 + n]);
  } else if (i < 3 * S + 2 * SF + 324) {
    int j = i - 3 * S - 2 * SF;
    biasCat[j] = (j < 216) ? boff_l[j] : ba_l[j - 216];
  }
}

// ---------------- bf16 MFMA GEMM: C = A @ Bt^T (+bias)(+relu) ----------------
// Staging via global_load_lds width=16 (DMA direct to LDS, contiguous 64B rows).
__global__ __launch_bounds__(256) void k_gemm_bf(
    const unsigned short* __restrict__ A, const unsigned short* __restrict__ Bt,
    const float* __restrict__ bias, float* __restrict__ Cf, unsigned short* __restrict__ Cb,
    int M, int K, int N, int relu) {
  __shared__ unsigned short As[128 * 32];
  __shared__ unsigned short Bs[128 * 32];
  int m0 = blockIdx.y * 128, n0 = blockIdx.x * 128;
  int t = threadIdx.x;
  int w = t >> 6, l = t & 63;
  int wm = w >> 1, wn = w & 1;
  int half = l >> 4, lr = l & 15;
  float4v acc[4][4] = {};
  for (int k0 = 0; k0 < K; k0 += 32) {
    #pragma unroll
    for (int i = 0; i < 2; ++i) {
      int c = w * 64 + i * 256 + l;           // 0..511
      int r = c >> 2, part = c & 3;
      int ldsOff = (w * 64 + i * 256) * 8;    // shorts; lane adds l*16 bytes
      __builtin_amdgcn_global_load_lds(
          (const AS1 unsigned int*)(A + (size_t)(m0 + r) * K + k0 + part * 8),
          (AS3 unsigned int*)(As + ldsOff), 16, 0, 0);
      __builtin_amdgcn_global_load_lds(
          (const AS1 unsigned int*)(Bt + (size_t)(n0 + r) * K + k0 + part * 8),
          (AS3 unsigned int*)(Bs + ldsOff), 16, 0, 0);
    }
    __syncthreads();
    short8 af[4], bfr[4];
    #pragma unroll
    for (int am = 0; am < 4; ++am)
      af[am] = *(const short8*)(&As[(wm * 64 + am * 16 + lr) * 32 + half * 8]);
    #pragma unroll
    for (int bn = 0; bn < 4; ++bn)
      bfr[bn] = *(const short8*)(&Bs[(wn * 64 + bn * 16 + lr) * 32 + half * 8]);
    #pragma unroll
    for (int am = 0; am < 4; ++am)
      #pragma unroll
      for (int bn = 0; bn < 4; ++bn)
        acc[am][bn] = __builtin_amdgcn_mfma_f32_16x16x32_bf16(af[am], bfr[bn], acc[am][bn], 0, 0, 0);
    __syncthreads();
  }
  #pragma unroll
  for (int am = 0; am < 4; ++am) {
    #pragma unroll
    for (int bn = 0; bn < 4; ++bn) {
      int gc = n0 + wn * 64 + bn * 16 + lr;
      if (gc < N) {
        float bv = bias ? bias[gc] : 0.f;
        int gr0 = m0 + wm * 64 + am * 16 + half * 4;
        #pragma unroll
        for (int r = 0; r < 4; ++r) {
          float v = acc[am][bn][r] + bv;
          if (relu) v = fmaxf(v, 0.f);
          size_t oi = (size_t)(gr0 + r) * N + gc;
          if (Cf) Cf[oi] = v;
          else Cb[oi] = f2bf(v);
        }
      }
    }
  }
}

// ---------------- coords+softmax: one thread per (row, head) ----------------
__global__ void k_coords(const unsigned short* __restrict__ OAB, float4* __restrict__ CRD) {
  int idx = blockIdx.x * 256 + threadIdx.x;
  if (idx >= NB * NPIX * NH) return;
  int row = idx / NH, h = idx % NH;
  int n = row & (NPIX - 1);
  int hh = n >> 6, ww = n & 63;
  float refx = ((float)ww + 0.5f) / (float)WDIM;
  float refy = ((float)hh + 0.5f) / (float)HDIM;
  const unsigned short* oab = OAB + (size_t)row * 324;
  float f[NPTS];
  #pragma unroll
  for (int j = 0; j < NPTS; ++j) f[j] = bf2f(oab[216 + h * 9 + j]);
  float m = f[0];
  #pragma unroll
  for (int j = 1; j < NPTS; ++j) m = fmaxf(m, f[j]);
  float s = 0.f;
  #pragma unroll
  for (int j = 0; j < NPTS; ++j) { f[j] = expf(f[j] - m); s += f[j]; }
  float inv = 1.f / s;
  float4* crd = CRD + (size_t)row * 108 + h * 9;
  #pragma unroll
  for (int p = 0; p < NPTS; ++p) {
    float ox = bf2f(oab[h * 18 + p * 2 + 0]);
    float oy = bf2f(oab[h * 18 + p * 2 + 1]);
    float lx = refx + ox / (float)WDIM;
    float ly = refy + oy / (float)HDIM;
    float xs = lx * (float)WDIM - 0.5f;
    float ys = ly * (float)HDIM - 0.5f;
    float x0f = floorf(xs), y0f = floorf(ys);
    int x0 = (int)x0f, y0 = (int)y0f;
    float4 o;
    o.x = xs - x0f;
    o.y = ys - y0f;
    o.z = f[p] * inv;
    o.w = __int_as_float((y0 << 16) | (x0 & 0xFFFF));
    crd[p] = o;
  }
}

// ---------------- gather: 4 channels per thread, float4 gathers ----------------
__global__ __launch_bounds__(256) void k_gather(
    const float* __restrict__ V, const float4* __restrict__ CRD,
    uint2* __restrict__ ATTu) {
  int idx = blockIdx.x * 256 + threadIdx.x;
  if (idx >= NB * NPIX * (CE / 4)) return;
  int row = idx / (CE / 4), cq = idx % (CE / 4);
  int c = cq * 4;
  int h = c >> 5;
  int b = row >> 12;
  const float* vb = V + (size_t)b * NPIX * CE;
  const float4* crd = CRD + (size_t)row * 108 + h * 9;
  float a0 = 0.f, a1 = 0.f, a2 = 0.f, a3 = 0.f;
  #pragma unroll
  for (int p = 0; p < NPTS; ++p) {
    float4 o = crd[p];
    int pk = __float_as_int(o.w);
    int x0 = (int)(short)(pk & 0xFFFF);
    int y0 = pk >> 16;
    float wx = o.x, wy = o.y, aw = o.z;
    float4 g00 = sample4(vb, x0,     y0,     c);
    float4 g01 = sample4(vb, x0 + 1, y0,     c);
    float4 g10 = sample4(vb, x0,     y0 + 1, c);
    float4 g11 = sample4(vb, x0 + 1, y0 + 1, c);
    float w00 = (1.f - wx) * (1.f - wy), w01 = wx * (1.f - wy);
    float w10 = (1.f - wx) * wy,         w11 = wx * wy;
    a0 += aw * (g00.x * w00 + g01.x * w01 + g10.x * w10 + g11.x * w11);
    a1 += aw * (g00.y * w00 + g01.y * w01 + g10.y * w10 + g11.y * w11);
    a2 += aw * (g00.z * w00 + g01.z * w01 + g10.z * w10 + g11.z * w11);
    a3 += aw * (g00.w * w00 + g01.w * w01 + g10.w * w10 + g11.w * w11);
  }
  uint2 pk2;
  pk2.x = (unsigned)f2bf(a0) | ((unsigned)f2bf(a1) << 16);
  pk2.y = (unsigned)f2bf(a2) | ((unsigned)f2bf(a3) << 16);
  ATTu[(size_t)row * (CE / 4) + cq] = pk2;
}

// ---------------- LayerNorm(X + T), 4 rows/block, fused epilogues ----------------
__global__ __launch_bounds__(256) void k_ln(
    float* __restrict__ X, const float* __restrict__ T,
    const float* __restrict__ g, const float* __restrict__ bb,
    unsigned short* __restrict__ xbOut,
    const float* __restrict__ posp, const float* __restrict__ notp,
    unsigned short* __restrict__ qb, unsigned short* __restrict__ vbin,
    float* __restrict__ outp) {
  int t = threadIdx.x;
  int row = blockIdx.x * 4 + (t >> 6);
  int lane = t & 63;
  float* xr = X + (long)row * CE;
  const float* tr = T + (long)row * CE;
  float v[6]; float s = 0.f;
  #pragma unroll
  for (int i = 0; i < 6; ++i) { v[i] = xr[lane + 64 * i] + tr[lane + 64 * i]; s += v[i]; }
  #pragma unroll
  for (int o = 32; o > 0; o >>= 1) s += __shfl_down(s, o, 64);
  s = __shfl(s, 0, 64);
  float m = s / (float)CE;
  float var = 0.f;
  #pragma unroll
  for (int i = 0; i < 6; ++i) { float d = v[i] - m; var += d * d; }
  #pragma unroll
  for (int o = 32; o > 0; o >>= 1) var += __shfl_down(var, o, 64);
  var = __shfl(var, 0, 64);
  float rst = rsqrtf(var / (float)CE + 1e-5f);
  float nprow = notp ? notp[row] : 0.f;
  int b = row >> 12, n = row & (NPIX - 1);
  #pragma unroll
  for (int i = 0; i < 6; ++i) {
    int c = lane + 64 * i;
    float xn = (v[i] - m) * rst * g[c] + bb[c];
    if (outp) outp[((long)b * NROW + n) * CE + c] = xn;
    else xr[c] = xn;
    if (xbOut) xbOut[(long)row * CE + c] = f2bf(xn);
    if (qb) {
      qb[(long)row * CE + c] = f2bf(xn + posp[(long)row * CE + c]);
      vbin[(long)row * CE + c] = f2bf(xn * nprow);
    }
  }
}

// ---------------- centers -> output ----------------
__global__ void k_out_cen(const double* __restrict__ fg, const double* __restrict__ bg,
                          float* __restrict__ out) {
  int i = blockIdx.x * 256 + threadIdx.x;
  const int tot = NB * (KFG + KBG) * CE;
  if (i >= tot) return;
  int c = i % CE;
  int r = i / CE;
  int rr = r % (KFG + KBG);
  int b = r / (KFG + KBG);
  float v;
  if (rr < KFG) v = (float)fg[((long)b * KFG + rr) * CE + c];
  else v = (float)bg[((long)b * KBG + (rr - KFG)) * CE + c];
  out[((long)b * NROW + NPIX + rr) * CE + c] = v;
}

extern "C" void kernel_launch(void* const* d_in, const int* in_sizes, int n_in,
                              void* d_out, int out_size, void* d_ws, size_t ws_size,
                              hipStream_t stream) {
  (void)in_sizes; (void)n_in; (void)out_size; (void)ws_size;
  const float* s_x  = (const float*)d_in[0];
  const float* s_pm = (const float*)d_in[1];
  const float* s_sm = (const float*)d_in[2];
  const float* Wv   = (const float*)d_in[3];
  const float* bv   = (const float*)d_in[4];
  const float* Woff = (const float*)d_in[5];
  const float* boff = (const float*)d_in[6];
  const float* Wa   = (const float*)d_in[7];
  const float* ba   = (const float*)d_in[8];
  const float* Wout = (const float*)d_in[9];
  const float* bout = (const float*)d_in[10];
  const float* ln1g = (const float*)d_in[11];
  const float* ln1b = (const float*)d_in[12];
  const float* Wf1  = (const float*)d_in[13];
  const float* Wf2  = (const float*)d_in[14];
  const float* ln2g = (const float*)d_in[15];
  const float* ln2b = (const float*)d_in[16];
  float* out = (float*)d_out;
  char* pb = (char*)d_ws;

  const long BN  = (long)NB * NPIX;      // 16384
  const long BNC = BN * CE;              // 6291456

  float* X    = (float*)pb; pb += BNC * 4;
  float* POS  = (float*)pb; pb += BNC * 4;
  float* V    = (float*)pb; pb += BNC * 4;
  float* T2   = (float*)pb; pb += BNC * 4;
  double* PF  = (double*)V;    // NCHUNK*NB*KFG*CE*8 = 7.9 MB  (< 24 MB)
  double* PB  = (double*)T2;   // NCHUNK*NB*KBG*CE*8 = 19.7 MB (< 24 MB)
  unsigned short* QB   = (unsigned short*)pb; pb += BNC * 2;
  unsigned short* VBin = (unsigned short*)pb; pb += BNC * 2;
  unsigned short* T1b  = (unsigned short*)pb; pb += BNC * 2;
  unsigned short* Zbf  = QB;   // FFN hidden aliases QB+VBin+T1b
  unsigned short* XB   = (unsigned short*)pb; pb += BNC * 2;
  unsigned short* OAB  = (unsigned short*)pb; pb += BN * 324 * 2;
  float4* CRD = (float4*)pb; pb += BN * 108 * 16;
  const int S_W = 147456, S_F = 442368;
  unsigned short* WT[NLAYERS][5];
  float* biasCat[NLAYERS];
  for (int l = 0; l < NLAYERS; ++l) {
    WT[l][0] = (unsigned short*)pb; pb += S_W * 2;
    WT[l][1] = (unsigned short*)pb; pb += S_W * 2;
    WT[l][2] = (unsigned short*)pb; pb += S_W * 2;
    WT[l][3] = (unsigned short*)pb; pb += S_F * 2;
    WT[l][4] = (unsigned short*)pb; pb += S_F * 2;
    biasCat[l] = (float*)pb; pb += 324 * 4;
  }
  float* padf = (float*)pb; pb += BN * 4;
  float* objf = (float*)pb; pb += BN * 4;
  float* notp = (float*)pb; pb += BN * 4;
  float* wfg  = (float*)pb; pb += BN * 4;
  float* wbg  = (float*)pb; pb += BN * 4;
  float* yvf  = (float*)pb; pb += BN * 4;
  float* xvf  = (float*)pb; pb += BN * 4;
  float* invdt = (float*)pb; pb += CE * 4;
  pb = (char*)(((size_t)pb + 7) & ~(size_t)7);
  double* xsq  = (double*)pb; pb += BN * 8;
  double* DF   = (double*)pb; pb += BN * KFG * 8;
  double* DB   = (double*)pb; pb += BN * KBG * 8;
  double* cFgA = (double*)pb; pb += (long)NB * KFG * CE * 8;
  double* cFgB = (double*)pb; pb += (long)NB * KFG * CE * 8;
  double* cBgA = (double*)pb; pb += (long)NB * KBG * CE * 8;
  double* cBgB = (double*)pb; pb += (long)NB * KBG * CE * 8;
  double* denF = (double*)pb; pb += NB * KFG * 8;
  double* denB = (double*)pb; pb += NB * KBG * 8;   // contiguous after denF

  int bn = (int)BN;
  int cvtBlocks = (int)((BNC + 255) / 256);

  k_masks<<<(bn + 255) / 256, 256, 0, stream>>>(s_pm, s_sm, padf, objf, notp, wfg, wbg);
  k_transpose<<<dim3(NPIX / 64, CE / 64, NB), 256, 0, stream>>>(s_x, X);
  k_xsq<<<bn, 64, 0, stream>>>(X, xsq);
  k_cums<<<NB, 128, 0, stream>>>(padf, yvf, xvf, invdt);
  k_cvtQV<<<cvtBlocks, 256, 0, stream>>>(X, yvf, xvf, invdt, notp, POS, QB, VBin);

  const int CVTW_TOT = 3 * S_W + 2 * S_F + 324;
  for (int l = 0; l < NLAYERS; ++l) {
    k_cvtW_all<<<(CVTW_TOT + 255) / 256, 256, 0, stream>>>(
        Wv + (long)l * CE * CE, Woff + (long)l * CE * 216, Wa + (long)l * CE * 108,
        Wout + (long)l * CE * CE, Wf1 + (long)l * CE * 1152, Wf2 + (long)l * 1152 * CE,
        boff + l * 216, ba + l * 108,
        WT[l][0], WT[l][1], WT[l][2], WT[l][3], WT[l][4], biasCat[l]);
  }

  // ---- kmeans: dots -> (argmin+hist+reduce1) -> reduce2+final ----
  double *srcF = cFgA, *dstF = cFgB, *srcB = cBgA, *dstB = cBgB;
  k_kinit<<<NB, 256, 0, stream>>>(X, wfg, srcF, KFG);
  k_kinit<<<NB, 256, 0, stream>>>(X, wbg, srcB, KBG);
  int naF = NB * KFG * CE, naB = NB * KBG * CE;
  for (int it = 0; it < NITER; ++it) {
    k_dots<<<dim3(bn / 256, 7), 256, 0, stream>>>(X, xsq, srcF, srcB, DF, DB, denF);
    k_armred<<<dim3(NCHUNK, CE / 128, NB * 2), 128, 0, stream>>>(
        X, DF, DB, wfg, wbg, denF, denB, PF, PB);
    k_reduce2f<<<(naF + naB + 255) / 256, 256, 0, stream>>>(
        PF, denF, srcF, dstF, naF, PB, denB, srcB, dstB, naB);
    double* tmp;
    tmp = srcF; srcF = dstF; dstF = tmp;
    tmp = srcB; srcB = dstB; dstB = tmp;
  }
  double* fgC = srcF; double* bgC = srcB;

  // ---- layers ----
  for (int l = 0; l < NLAYERS; ++l) {
    const float* bv_l   = bv   + l * CE;
    const float* bout_l = bout + l * CE;
    int last = (l == NLAYERS - 1);

    k_gemm_bf<<<dim3(3, 128), 256, 0, stream>>>(VBin, WT[l][0], bv_l, V, (unsigned short*)nullptr,
                                                bn, CE, 384, 0);
    k_gemm_bf<<<dim3(3, 128), 256, 0, stream>>>(QB, WT[l][1], biasCat[l], (float*)nullptr, OAB,
                                                bn, CE, 324, 0);
    k_coords<<<(bn * NH + 255) / 256, 256, 0, stream>>>(OAB, CRD);
    k_gather<<<(bn * (CE / 4) + 255) / 256, 256, 0, stream>>>(V, CRD, (uint2*)T1b);
    k_gemm_bf<<<dim3(3, 128), 256, 0, stream>>>(T1b, WT[l][2], bout_l, T2, (unsigned short*)nullptr,
                                                bn, CE, 384, 0);
    k_ln<<<bn / 4, 256, 0, stream>>>(X, T2, ln1g + l * CE, ln1b + l * CE,
                                     XB, (const float*)nullptr, (const float*)nullptr,
                                     (unsigned short*)nullptr, (unsigned short*)nullptr,
                                     (float*)nullptr);
    k_gemm_bf<<<dim3(9, 128), 256, 0, stream>>>(XB, WT[l][3], (const float*)nullptr,
                                                (float*)nullptr, Zbf, bn, CE, 1152, 1);
    k_gemm_bf<<<dim3(3, 128), 256, 0, stream>>>(Zbf, WT[l][4], (const float*)nullptr,
                                                T2, (unsigned short*)nullptr, bn, 1152, 384, 0);
    if (!last) {
      k_ln<<<bn / 4, 256, 0, stream>>>(X, T2, ln2g + l * CE, ln2b + l * CE,
                                       (unsigned short*)nullptr, POS, notp, QB, VBin,
                                       (float*)nullptr);
    } else {
      k_ln<<<bn / 4, 256, 0, stream>>>(X, T2, ln2g + l * CE, ln2b + l * CE,
                                       (unsigned short*)nullptr, (const float*)nullptr,
                                       (const float*)nullptr, (unsigned short*)nullptr,
                                       (unsigned short*)nullptr, out);
    }
  }

  k_out_cen<<<(NB * (KFG + KBG) * CE + 255) / 256, 256, 0, stream>>>(fgC, bgC, out);
}